// Round 10
// baseline (293.771 us; speedup 1.0000x reference)
//
#include <hip/hip_runtime.h>
#include <math.h>

#define NHEADS 8
#define C 512
#define HW 1024
#define HD 64

typedef __bf16 bf16x8 __attribute__((ext_vector_type(8)));
typedef __bf16 bf16x4 __attribute__((ext_vector_type(4)));
typedef float f32x4 __attribute__((ext_vector_type(4)));

// ---------------- weight fp32 -> bf16 convert (both W's in one launch) ------
__global__ __launch_bounds__(256) void wcvt_kernel(const float* __restrict__ w1,
                                                   __bf16* __restrict__ o1,
                                                   const float* __restrict__ w2,
                                                   __bf16* __restrict__ o2) {
  int id = blockIdx.x * 2048 + threadIdx.x * 8;
  const float* src;
  __bf16* dst;
  int off;
  if (id < 786432) { src = w1; dst = o1; off = id; }
  else { src = w2; dst = o2; off = id - 786432; }
  float4 a = *(const float4*)(src + off);
  float4 b = *(const float4*)(src + off + 4);
  bf16x8 o;
  o[0] = (__bf16)a.x; o[1] = (__bf16)a.y; o[2] = (__bf16)a.z; o[3] = (__bf16)a.w;
  o[4] = (__bf16)b.x; o[5] = (__bf16)b.y; o[6] = (__bf16)b.z; o[7] = (__bf16)b.w;
  *(bf16x8*)(dst + off) = o;
}

// ---------------- GroupNorm -> xnT [b][j=hw][c] bf16 ----------------
__global__ __launch_bounds__(256) void gn_kernel(const float* __restrict__ x,
                                                 const float* __restrict__ gamma,
                                                 const float* __restrict__ beta,
                                                 __bf16* __restrict__ xnT) {
  int b = blockIdx.x >> 5, g = blockIdx.x & 31;
  const size_t base = ((size_t)b * C + (size_t)g * 16) * HW;
  const float4* xp = (const float4*)(x + base);
  int tid = threadIdx.x;

  float s = 0.f, ss = 0.f;
  float4 v[16];
#pragma unroll
  for (int it = 0; it < 16; it++) {
    v[it] = xp[tid + it * 256];
    s += v[it].x + v[it].y + v[it].z + v[it].w;
    ss += v[it].x * v[it].x + v[it].y * v[it].y + v[it].z * v[it].z + v[it].w * v[it].w;
  }
#pragma unroll
  for (int off = 32; off > 0; off >>= 1) {
    s += __shfl_down(s, off);
    ss += __shfl_down(ss, off);
  }
  __shared__ float red[8];
  __shared__ float mi[2];
  int wid = tid >> 6;
  if ((tid & 63) == 0) { red[wid] = s; red[4 + wid] = ss; }
  __syncthreads();
  if (tid == 0) {
    float S = red[0] + red[1] + red[2] + red[3];
    float SS = red[4] + red[5] + red[6] + red[7];
    float mean = S * (1.f / 16384.f);
    float var = SS * (1.f / 16384.f) - mean * mean;
    mi[0] = mean;
    mi[1] = rsqrtf(var + 1e-5f);
  }
  __syncthreads();
  float mean = mi[0], inv = mi[1];
  float ga[16], be[16];
#pragma unroll
  for (int it = 0; it < 16; it++) {
    float g_ = gamma[g * 16 + it] * inv;
    ga[it] = g_;
    be[it] = beta[g * 16 + it] - mean * g_;
  }
  __bf16* dstb = xnT + ((size_t)b * HW + (size_t)tid * 4) * C + g * 16;
#pragma unroll
  for (int jj = 0; jj < 4; jj++) {
    bf16x8 w0, w1;
#pragma unroll
    for (int e = 0; e < 8; e++) {
      w0[e] = (__bf16)(((const float*)&v[e])[jj] * ga[e] + be[e]);
      w1[e] = (__bf16)(((const float*)&v[e + 8])[jj] * ga[e + 8] + be[e + 8]);
    }
    *(bf16x8*)(dstb + (size_t)jj * C) = w0;
    *(bf16x8*)(dstb + (size_t)jj * C + 8) = w1;
  }
}

// ---------------- MFMA GEMM: D = R @ C^T, both [rows][512] bf16 row-major ---
// 128x128 tile, BK=64, reg-prefetch double-buffered LDS (one barrier/iter).
template <int EPI>
__global__ __launch_bounds__(256) void gemm_rr(const __bf16* __restrict__ Rp, size_t Rbs,
                                               const __bf16* __restrict__ Cp, size_t Cbs,
                                               const float* __restrict__ bias,
                                               __bf16* __restrict__ q_or_v,
                                               __bf16* __restrict__ kT,
                                               const float* __restrict__ resid,
                                               float* __restrict__ Yout) {
  int bx = blockIdx.x, by = blockIdx.y, b = blockIdx.z;
  int tid = threadIdx.x, wid = tid >> 6, lane = tid & 63;
  int l15 = lane & 15, lhi = lane >> 4;
  int wr = wid >> 1, wc = wid & 1;

  const __bf16* Rb = Rp + (size_t)b * Rbs + (size_t)by * 128 * 512;
  const __bf16* Cb = Cp + (size_t)b * Cbs + (size_t)bx * 128 * 512;

  // double buffer: buf k at (k&1)<<15; Rs at +0, Cs at +16384
  __shared__ __align__(16) char smem[65536];

  f32x4 acc[4][4] = {};
  int srow = tid >> 1, sc0 = (tid & 1) * 4;

  // swizzled LDS chunk offsets for this thread's 4 R/C chunks
  int soff[4];
#pragma unroll
  for (int q = 0; q < 4; q++)
    soff[q] = srow * 128 + (((sc0 + q) ^ (srow & 7)) << 4);

  uint4 rr[4], cr[4];
  // tile 0: load + store into buf0
#pragma unroll
  for (int q = 0; q < 4; q++) {
    rr[q] = *(const uint4*)(Rb + (size_t)srow * 512 + (sc0 + q) * 8);
    cr[q] = *(const uint4*)(Cb + (size_t)srow * 512 + (sc0 + q) * 8);
  }
#pragma unroll
  for (int q = 0; q < 4; q++) {
    *(uint4*)(smem + soff[q]) = rr[q];
    *(uint4*)(smem + 16384 + soff[q]) = cr[q];
  }

  for (int kk8 = 0; kk8 < 8; kk8++) {
    if (kk8 < 7) {  // prefetch next K-tile into regs
      int kk = (kk8 + 1) * 64;
#pragma unroll
      for (int q = 0; q < 4; q++) {
        rr[q] = *(const uint4*)(Rb + (size_t)srow * 512 + kk + (sc0 + q) * 8);
        cr[q] = *(const uint4*)(Cb + (size_t)srow * 512 + kk + (sc0 + q) * 8);
      }
    }
    __syncthreads();
    const char* Rs = smem + ((kk8 & 1) << 15);
    const char* Cs = Rs + 16384;
#pragma unroll
    for (int ks = 0; ks < 2; ks++) {
      bf16x8 ar[4], br[4];
      int c = ks * 4 + lhi;
#pragma unroll
      for (int m = 0; m < 4; m++) {
        int row = wr * 64 + m * 16 + l15;
        ar[m] = *(const bf16x8*)(Rs + row * 128 + ((c ^ (row & 7)) << 4));
      }
#pragma unroll
      for (int n = 0; n < 4; n++) {
        int row = wc * 64 + n * 16 + l15;
        br[n] = *(const bf16x8*)(Cs + row * 128 + ((c ^ (row & 7)) << 4));
      }
#pragma unroll
      for (int m = 0; m < 4; m++)
#pragma unroll
        for (int n = 0; n < 4; n++)
          acc[m][n] = __builtin_amdgcn_mfma_f32_16x16x32_bf16(ar[m], br[n], acc[m][n], 0, 0, 0);
    }
    if (kk8 < 7) {  // write prefetched regs into the other buffer
      char* Rd = smem + (((kk8 + 1) & 1) << 15);
#pragma unroll
      for (int q = 0; q < 4; q++) {
        *(uint4*)(Rd + soff[q]) = rr[q];
        *(uint4*)(Rd + 16384 + soff[q]) = cr[q];
      }
    }
  }

  int rbase = by * 128 + wr * 64;
  int cbase = bx * 128 + wc * 64;

  if (EPI == 0) {
#pragma unroll
    for (int n = 0; n < 4; n++) {
      int col = cbase + n * 16 + l15;
      int sec = col >> 9;
      int h = (col >> 6) & 7;
      int d = col & 63;
      __bf16* dst0 = (sec ? kT : q_or_v) + ((size_t)b * 8 + h) * (size_t)(HW * HD) + d;
      float bs = bias[col];
#pragma unroll
      for (int m = 0; m < 4; m++)
#pragma unroll
        for (int r = 0; r < 4; r++) {
          int i = rbase + m * 16 + lhi * 4 + r;
          dst0[(size_t)i * HD] = (__bf16)(acc[m][n][r] + bs);
        }
    }
  } else if (EPI == 1) {
#pragma unroll
    for (int m = 0; m < 4; m++)
#pragma unroll
      for (int r = 0; r < 4; r++) {
        int row = rbase + m * 16 + lhi * 4 + r;
        int h = row >> 6, d = row & 63;
        float bs = bias[row];
        __bf16* dst = q_or_v + (((size_t)b * 8 + h) * HD + d) * HW;
#pragma unroll
        for (int n = 0; n < 4; n++) {
          int j = cbase + n * 16 + l15;
          dst[j] = (__bf16)(acc[m][n][r] + bs);
        }
      }
  } else {
#pragma unroll
    for (int m = 0; m < 4; m++)
#pragma unroll
      for (int r = 0; r < 4; r++) {
        int o = rbase + m * 16 + lhi * 4 + r;
        float bs = bias[o];
        size_t base2 = ((size_t)b * C + o) * HW;
#pragma unroll
        for (int n = 0; n < 4; n++) {
          int j = cbase + n * 16 + l15;
          Yout[base2 + j] = acc[m][n][r] + bs + resid[base2 + j];
        }
      }
  }
}

// ---------------- MFMA flash attention (prefetch dbuf + defer-max + exp2) --
// qT,kT: [64 heads][1024][64] bf16 ; vN: [64 heads][64][1024] bf16
// Grid: flat 512; bh = id&63 so all 8 q-tiles of a head share one XCD's L2.
__global__ __launch_bounds__(256) void attn_mfma_kernel(const __bf16* __restrict__ qT,
                                                        const __bf16* __restrict__ kT,
                                                        const __bf16* __restrict__ vN,
                                                        __bf16* __restrict__ aT) {
  int bh = blockIdx.x & 63;
  int qt = blockIdx.x >> 6;
  int tid = threadIdx.x;
  int wid = tid >> 6;
  int lane = tid & 63;
  int l15 = lane & 15;
  int lhi = lane >> 4;

  const __bf16* qh = qT + (size_t)bh * HW * HD;
  const char* kh = (const char*)(kT + (size_t)bh * HW * HD);
  const char* vh = (const char*)(vN + (size_t)bh * HD * HW);

  __shared__ __align__(16) char smem[49152];
  char* pb = smem + 32768 + wid * 4096;

  int i0 = qt * 128 + wid * 32;

  // Q fragments, pre-scaled by (1/8)*log2(e) so softmax works in exp2 domain
  bf16x8 qf[2][2];
#pragma unroll
  for (int it = 0; it < 2; it++)
#pragma unroll
    for (int ks = 0; ks < 2; ks++) {
      int row = i0 + it * 16 + l15;
      bf16x8 qv = *(const bf16x8*)(qh + (size_t)row * HD + ks * 32 + lhi * 8);
#pragma unroll
      for (int e = 0; e < 8; e++) qv[e] = (__bf16)((float)qv[e] * 0.180336884f);
      qf[it][ks] = qv;
    }

  int sr = tid >> 3, sc = tid & 7;
  int sr2 = sr + 32;
  int swz1 = sr * 128 + ((sc ^ (sr & 7)) << 4);
  int swz2 = sr2 * 128 + ((sc ^ (sr2 & 7)) << 4);

  uint4 kr0, kr1, vr0, vr1;
  {
    kr0 = *(const uint4*)(kh + (size_t)sr * 128 + sc * 16);
    kr1 = *(const uint4*)(kh + (size_t)sr2 * 128 + sc * 16);
    vr0 = *(const uint4*)(vh + (size_t)sr * 2048 + sc * 16);
    vr1 = *(const uint4*)(vh + (size_t)sr2 * 2048 + sc * 16);
    *(uint4*)(smem + swz1) = kr0;
    *(uint4*)(smem + swz2) = kr1;
    *(uint4*)(smem + 8192 + swz1) = vr0;
    *(uint4*)(smem + 8192 + swz2) = vr1;
  }

  f32x4 accO[2][4] = {};
  f32x4 lacc[2] = {};
  float m[2][4];
#pragma unroll
  for (int it = 0; it < 2; it++)
#pragma unroll
    for (int r = 0; r < 4; r++) m[it][r] = -1e30f;

  bf16x8 ones;
#pragma unroll
  for (int e = 0; e < 8; e++) ones[e] = (__bf16)1.0f;

  for (int t = 0; t < 16; ++t) {
    if (t < 15) {
      int j0n = (t + 1) * 64;
      kr0 = *(const uint4*)(kh + (size_t)(j0n + sr) * 128 + sc * 16);
      kr1 = *(const uint4*)(kh + (size_t)(j0n + sr2) * 128 + sc * 16);
      vr0 = *(const uint4*)(vh + (size_t)sr * 2048 + j0n * 2 + sc * 16);
      vr1 = *(const uint4*)(vh + (size_t)sr2 * 2048 + j0n * 2 + sc * 16);
    }
    __syncthreads();
    const char* kt = smem + ((t & 1) << 14);
    const char* vt = kt + 8192;

    // ---- QK^T (scores already in log2 domain) ----
    f32x4 s_[2][4] = {};
#pragma unroll
    for (int ks = 0; ks < 2; ++ks)
#pragma unroll
      for (int jt = 0; jt < 4; ++jt) {
        int j = jt * 16 + l15;
        int c = ks * 4 + lhi;
        bf16x8 bk = *(const bf16x8*)(kt + j * 128 + ((c ^ (j & 7)) << 4));
        s_[0][jt] = __builtin_amdgcn_mfma_f32_16x16x32_bf16(qf[0][ks], bk, s_[0][jt], 0, 0, 0);
        s_[1][jt] = __builtin_amdgcn_mfma_f32_16x16x32_bf16(qf[1][ks], bk, s_[1][jt], 0, 0, 0);
      }

    // ---- defer-max online softmax (log2 domain) ----
    float lm[2][4];
    int ok = 1;
#pragma unroll
    for (int it = 0; it < 2; ++it)
#pragma unroll
      for (int r = 0; r < 4; r++) {
        lm[it][r] = fmaxf(fmaxf(s_[it][0][r], s_[it][1][r]),
                          fmaxf(s_[it][2][r], s_[it][3][r]));
        ok &= (lm[it][r] <= m[it][r] + 8.f);
      }
    if (!__all(ok)) {
#pragma unroll
      for (int it = 0; it < 2; ++it) {
        float pm[4];
#pragma unroll
        for (int r = 0; r < 4; r++) pm[r] = lm[it][r];
#pragma unroll
        for (int off = 1; off < 16; off <<= 1)
#pragma unroll
          for (int r = 0; r < 4; r++) pm[r] = fmaxf(pm[r], __shfl_xor(pm[r], off));
#pragma unroll
        for (int r = 0; r < 4; r++) {
          float nm = fmaxf(m[it][r], pm[r]);
          float corr = exp2f(m[it][r] - nm);
          m[it][r] = nm;
          lacc[it][r] *= corr;
#pragma unroll
          for (int dt = 0; dt < 4; ++dt) accO[it][dt][r] *= corr;
        }
      }
    }
    // P = 2^(s - m), store bf16 to per-wave LDS
#pragma unroll
    for (int it = 0; it < 2; ++it)
#pragma unroll
      for (int jt = 0; jt < 4; ++jt)
#pragma unroll
        for (int r = 0; r < 4; r++) {
          float p = exp2f(s_[it][jt][r] - m[it][r]);
          int row = it * 16 + lhi * 4 + r;
          int j = jt * 16 + l15;
          int off2 = row * 128 + (((j >> 3) ^ (row & 7)) << 4) + (j & 7) * 2;
          *(__bf16*)(pb + off2) = (__bf16)p;
        }

    // ---- PV + rowsum-by-MFMA ----
#pragma unroll
    for (int kj = 0; kj < 2; ++kj) {
      bf16x8 pa[2];
#pragma unroll
      for (int it = 0; it < 2; ++it) {
        int row = it * 16 + l15;
        int c = kj * 4 + lhi;
        pa[it] = *(const bf16x8*)(pb + row * 128 + ((c ^ (row & 7)) << 4));
      }
      lacc[0] = __builtin_amdgcn_mfma_f32_16x16x32_bf16(pa[0], ones, lacc[0], 0, 0, 0);
      lacc[1] = __builtin_amdgcn_mfma_f32_16x16x32_bf16(pa[1], ones, lacc[1], 0, 0, 0);
#pragma unroll
      for (int dt = 0; dt < 4; ++dt) {
        int d = dt * 16 + l15;
        int c = kj * 4 + lhi;
        bf16x8 bv = *(const bf16x8*)(vt + d * 128 + ((c ^ (d & 7)) << 4));
        accO[0][dt] = __builtin_amdgcn_mfma_f32_16x16x32_bf16(pa[0], bv, accO[0][dt], 0, 0, 0);
        accO[1][dt] = __builtin_amdgcn_mfma_f32_16x16x32_bf16(pa[1], bv, accO[1][dt], 0, 0, 0);
      }
    }

    if (t < 15) {
      char* ktn = smem + (((t + 1) & 1) << 14);
      *(uint4*)(ktn + swz1) = kr0;
      *(uint4*)(ktn + swz2) = kr1;
      *(uint4*)(ktn + 8192 + swz1) = vr0;
      *(uint4*)(ktn + 8192 + swz2) = vr1;
    }
  }

  // epilogue: per-wave LDS transpose -> aT[b][i][h*64+d] bf16 coalesced
  __syncthreads();
  __bf16* Lo = (__bf16*)(smem + wid * 4608);  // [32][72] bf16
#pragma unroll
  for (int it = 0; it < 2; ++it)
#pragma unroll
    for (int r = 0; r < 4; r++) {
      float inv = 1.f / lacc[it][r];
      int iloc = it * 16 + lhi * 4 + r;
#pragma unroll
      for (int dt = 0; dt < 4; ++dt)
        Lo[iloc * 72 + dt * 16 + l15] = (__bf16)(accO[it][dt][r] * inv);
    }
  __syncthreads();
  int b = bh >> 3, hh = bh & 7;
  int iloc = lane >> 1, dh = (lane & 1) * 32;
  __bf16* dst = aT + ((size_t)b * HW + i0 + iloc) * C + hh * 64 + dh;
  const __bf16* srcl = Lo + iloc * 72 + dh;
#pragma unroll
  for (int s2 = 0; s2 < 4; s2++)
    *(uint4*)(dst + s2 * 8) = *(const uint4*)(srcl + s2 * 8);
}

extern "C" void kernel_launch(void* const* d_in, const int* in_sizes, int n_in,
                              void* d_out, int out_size, void* d_ws, size_t ws_size,
                              hipStream_t stream) {
  const float* x = (const float*)d_in[0];
  const float* gamma = (const float*)d_in[1];
  const float* beta = (const float*)d_in[2];
  const float* w_qkv = (const float*)d_in[3];
  const float* b_qkv = (const float*)d_in[4];
  const float* w_out = (const float*)d_in[5];
  const float* b_out = (const float*)d_in[6];
  float* out = (float*)d_out;

  char* ws = (char*)d_ws;
  const size_t MB = 1024 * 1024;
  __bf16* xnT = (__bf16*)ws;                  // 8 MB [8][1024][512]
  __bf16* qT  = (__bf16*)(ws + 8 * MB);       // 8 MB [64][1024][64]
  __bf16* kT  = (__bf16*)(ws + 16 * MB);      // 8 MB
  __bf16* vN  = (__bf16*)(ws + 24 * MB);      // 8 MB [64][64][1024]
  __bf16* aT  = (__bf16*)(ws + 32 * MB);      // 8 MB [8][1024][512]
  __bf16* wbq = (__bf16*)(ws + 40 * MB);      // 1.5 MB [1536][512]
  __bf16* wbo = (__bf16*)(ws + 42 * MB);      // 0.5 MB [512][512]

  // 1. weights -> bf16
  wcvt_kernel<<<dim3(512), 256, 0, stream>>>(w_qkv, wbq, w_out, wbo);
  // 2. GroupNorm -> xnT bf16 [b][j][c]
  gn_kernel<<<dim3(256), 256, 0, stream>>>(x, gamma, beta, xnT);
  // 3. Q,K projection: D[j][o] = xnT @ Wqk^T
  gemm_rr<0><<<dim3(8, 8, 8), 256, 0, stream>>>(xnT, (size_t)HW * C, wbq, 0,
                                                b_qkv, qT, kT, nullptr, nullptr);
  // 4. V projection: D[d'][j] = Wv @ xnT^T
  gemm_rr<1><<<dim3(8, 4, 8), 256, 0, stream>>>(wbq + (size_t)1024 * 512, 0, xnT, (size_t)HW * C,
                                                b_qkv + 1024, vN, nullptr, nullptr, nullptr);
  // 5. MFMA flash attention -> aT bf16 [b][j][c] (XCD-local grid)
  attn_mfma_kernel<<<dim3(512), 256, 0, stream>>>(qT, kT, vN, aT);
  // 6. Output projection: D[o][j] = Wout @ aT^T + bias + residual
  gemm_rr<2><<<dim3(8, 4, 8), 256, 0, stream>>>(wbo, 0, aT, (size_t)HW * C,
                                                b_out, nullptr, nullptr, x, out);
}

// Round 11
// 258.328 us; speedup vs baseline: 1.1372x; 1.1372x over previous
//
#include <hip/hip_runtime.h>
#include <math.h>

#define NHEADS 8
#define C 512
#define HW 1024
#define HD 64

typedef __bf16 bf16x8 __attribute__((ext_vector_type(8)));
typedef __bf16 bf16x4 __attribute__((ext_vector_type(4)));
typedef float f32x4 __attribute__((ext_vector_type(4)));

// ---------------- weight fp32 -> bf16 convert (both W's in one launch) ------
__global__ __launch_bounds__(256) void wcvt_kernel(const float* __restrict__ w1,
                                                   __bf16* __restrict__ o1,
                                                   const float* __restrict__ w2,
                                                   __bf16* __restrict__ o2) {
  int id = blockIdx.x * 2048 + threadIdx.x * 8;
  const float* src;
  __bf16* dst;
  int off;
  if (id < 786432) { src = w1; dst = o1; off = id; }
  else { src = w2; dst = o2; off = id - 786432; }
  float4 a = *(const float4*)(src + off);
  float4 b = *(const float4*)(src + off + 4);
  bf16x8 o;
  o[0] = (__bf16)a.x; o[1] = (__bf16)a.y; o[2] = (__bf16)a.z; o[3] = (__bf16)a.w;
  o[4] = (__bf16)b.x; o[5] = (__bf16)b.y; o[6] = (__bf16)b.z; o[7] = (__bf16)b.w;
  *(bf16x8*)(dst + off) = o;
}

// ---------------- GroupNorm -> xnT [b][j=hw][c] bf16 ----------------
__global__ __launch_bounds__(256) void gn_kernel(const float* __restrict__ x,
                                                 const float* __restrict__ gamma,
                                                 const float* __restrict__ beta,
                                                 __bf16* __restrict__ xnT) {
  int b = blockIdx.x >> 5, g = blockIdx.x & 31;
  const size_t base = ((size_t)b * C + (size_t)g * 16) * HW;
  const float4* xp = (const float4*)(x + base);
  int tid = threadIdx.x;

  float s = 0.f, ss = 0.f;
  float4 v[16];
#pragma unroll
  for (int it = 0; it < 16; it++) {
    v[it] = xp[tid + it * 256];
    s += v[it].x + v[it].y + v[it].z + v[it].w;
    ss += v[it].x * v[it].x + v[it].y * v[it].y + v[it].z * v[it].z + v[it].w * v[it].w;
  }
#pragma unroll
  for (int off = 32; off > 0; off >>= 1) {
    s += __shfl_down(s, off);
    ss += __shfl_down(ss, off);
  }
  __shared__ float red[8];
  __shared__ float mi[2];
  int wid = tid >> 6;
  if ((tid & 63) == 0) { red[wid] = s; red[4 + wid] = ss; }
  __syncthreads();
  if (tid == 0) {
    float S = red[0] + red[1] + red[2] + red[3];
    float SS = red[4] + red[5] + red[6] + red[7];
    float mean = S * (1.f / 16384.f);
    float var = SS * (1.f / 16384.f) - mean * mean;
    mi[0] = mean;
    mi[1] = rsqrtf(var + 1e-5f);
  }
  __syncthreads();
  float mean = mi[0], inv = mi[1];
  float ga[16], be[16];
#pragma unroll
  for (int it = 0; it < 16; it++) {
    float g_ = gamma[g * 16 + it] * inv;
    ga[it] = g_;
    be[it] = beta[g * 16 + it] - mean * g_;
  }
  __bf16* dstb = xnT + ((size_t)b * HW + (size_t)tid * 4) * C + g * 16;
#pragma unroll
  for (int jj = 0; jj < 4; jj++) {
    bf16x8 w0, w1;
#pragma unroll
    for (int e = 0; e < 8; e++) {
      w0[e] = (__bf16)(((const float*)&v[e])[jj] * ga[e] + be[e]);
      w1[e] = (__bf16)(((const float*)&v[e + 8])[jj] * ga[e + 8] + be[e + 8]);
    }
    *(bf16x8*)(dstb + (size_t)jj * C) = w0;
    *(bf16x8*)(dstb + (size_t)jj * C + 8) = w1;
  }
}

// ---------------- MFMA GEMM: D = R @ C^T, both [rows][512] bf16 row-major ---
// 128x128 tile, BK=64, reg-prefetch double-buffered LDS (one barrier/iter).
// __launch_bounds__(256, 1): min 1 wave/EU -> full VGPR budget, no spill of
// the 32 prefetch VGPRs (round-10 spill: WRITE_SIZE 3x inflated, pipes idle).
template <int EPI>
__global__ __launch_bounds__(256, 1) void gemm_rr(const __bf16* __restrict__ Rp, size_t Rbs,
                                                  const __bf16* __restrict__ Cp, size_t Cbs,
                                                  const float* __restrict__ bias,
                                                  __bf16* __restrict__ q_or_v,
                                                  __bf16* __restrict__ kT,
                                                  const float* __restrict__ resid,
                                                  float* __restrict__ Yout) {
  int bx = blockIdx.x, by = blockIdx.y, b = blockIdx.z;
  int tid = threadIdx.x, wid = tid >> 6, lane = tid & 63;
  int l15 = lane & 15, lhi = lane >> 4;
  int wr = wid >> 1, wc = wid & 1;

  const __bf16* Rb = Rp + (size_t)b * Rbs + (size_t)by * 128 * 512;
  const __bf16* Cb = Cp + (size_t)b * Cbs + (size_t)bx * 128 * 512;

  // double buffer: buf k at (k&1)<<15; Rs at +0, Cs at +16384
  __shared__ __align__(16) char smem[65536];

  f32x4 acc[4][4] = {};
  int srow = tid >> 1, sc0 = (tid & 1) * 4;

  int soff[4];
#pragma unroll
  for (int q = 0; q < 4; q++)
    soff[q] = srow * 128 + (((sc0 + q) ^ (srow & 7)) << 4);

  uint4 rr[4], cr[4];
#pragma unroll
  for (int q = 0; q < 4; q++) {
    rr[q] = *(const uint4*)(Rb + (size_t)srow * 512 + (sc0 + q) * 8);
    cr[q] = *(const uint4*)(Cb + (size_t)srow * 512 + (sc0 + q) * 8);
  }
#pragma unroll
  for (int q = 0; q < 4; q++) {
    *(uint4*)(smem + soff[q]) = rr[q];
    *(uint4*)(smem + 16384 + soff[q]) = cr[q];
  }

  for (int kk8 = 0; kk8 < 8; kk8++) {
    if (kk8 < 7) {  // prefetch next K-tile into regs
      int kk = (kk8 + 1) * 64;
#pragma unroll
      for (int q = 0; q < 4; q++) {
        rr[q] = *(const uint4*)(Rb + (size_t)srow * 512 + kk + (sc0 + q) * 8);
        cr[q] = *(const uint4*)(Cb + (size_t)srow * 512 + kk + (sc0 + q) * 8);
      }
    }
    __syncthreads();
    const char* Rs = smem + ((kk8 & 1) << 15);
    const char* Cs = Rs + 16384;
#pragma unroll
    for (int ks = 0; ks < 2; ks++) {
      bf16x8 ar[4], br[4];
      int c = ks * 4 + lhi;
#pragma unroll
      for (int m = 0; m < 4; m++) {
        int row = wr * 64 + m * 16 + l15;
        ar[m] = *(const bf16x8*)(Rs + row * 128 + ((c ^ (row & 7)) << 4));
      }
#pragma unroll
      for (int n = 0; n < 4; n++) {
        int row = wc * 64 + n * 16 + l15;
        br[n] = *(const bf16x8*)(Cs + row * 128 + ((c ^ (row & 7)) << 4));
      }
#pragma unroll
      for (int m = 0; m < 4; m++)
#pragma unroll
        for (int n = 0; n < 4; n++)
          acc[m][n] = __builtin_amdgcn_mfma_f32_16x16x32_bf16(ar[m], br[n], acc[m][n], 0, 0, 0);
    }
    if (kk8 < 7) {  // write prefetched regs into the other buffer
      char* Rd = smem + (((kk8 + 1) & 1) << 15);
#pragma unroll
      for (int q = 0; q < 4; q++) {
        *(uint4*)(Rd + soff[q]) = rr[q];
        *(uint4*)(Rd + 16384 + soff[q]) = cr[q];
      }
    }
  }

  int rbase = by * 128 + wr * 64;
  int cbase = bx * 128 + wc * 64;

  if (EPI == 0) {
#pragma unroll
    for (int n = 0; n < 4; n++) {
      int col = cbase + n * 16 + l15;
      int sec = col >> 9;
      int h = (col >> 6) & 7;
      int d = col & 63;
      __bf16* dst0 = (sec ? kT : q_or_v) + ((size_t)b * 8 + h) * (size_t)(HW * HD) + d;
      float bs = bias[col];
#pragma unroll
      for (int m = 0; m < 4; m++)
#pragma unroll
        for (int r = 0; r < 4; r++) {
          int i = rbase + m * 16 + lhi * 4 + r;
          dst0[(size_t)i * HD] = (__bf16)(acc[m][n][r] + bs);
        }
    }
  } else if (EPI == 1) {
#pragma unroll
    for (int m = 0; m < 4; m++)
#pragma unroll
      for (int r = 0; r < 4; r++) {
        int row = rbase + m * 16 + lhi * 4 + r;
        int h = row >> 6, d = row & 63;
        float bs = bias[row];
        __bf16* dst = q_or_v + (((size_t)b * 8 + h) * HD + d) * HW;
#pragma unroll
        for (int n = 0; n < 4; n++) {
          int j = cbase + n * 16 + l15;
          dst[j] = (__bf16)(acc[m][n][r] + bs);
        }
      }
  } else {
#pragma unroll
    for (int m = 0; m < 4; m++)
#pragma unroll
      for (int r = 0; r < 4; r++) {
        int o = rbase + m * 16 + lhi * 4 + r;
        float bs = bias[o];
        size_t base2 = ((size_t)b * C + o) * HW;
#pragma unroll
        for (int n = 0; n < 4; n++) {
          int j = cbase + n * 16 + l15;
          Yout[base2 + j] = acc[m][n][r] + bs + resid[base2 + j];
        }
      }
  }
}

// ---------------- MFMA flash attention (prefetch dbuf + defer-max + exp2) --
// qT,kT: [64 heads][1024][64] bf16 ; vN: [64 heads][64][1024] bf16
// Grid: flat 512; bh = id&63 so all 8 q-tiles of a head share one XCD's L2.
__global__ __launch_bounds__(256) void attn_mfma_kernel(const __bf16* __restrict__ qT,
                                                        const __bf16* __restrict__ kT,
                                                        const __bf16* __restrict__ vN,
                                                        __bf16* __restrict__ aT) {
  int bh = blockIdx.x & 63;
  int qt = blockIdx.x >> 6;
  int tid = threadIdx.x;
  int wid = tid >> 6;
  int lane = tid & 63;
  int l15 = lane & 15;
  int lhi = lane >> 4;

  const __bf16* qh = qT + (size_t)bh * HW * HD;
  const char* kh = (const char*)(kT + (size_t)bh * HW * HD);
  const char* vh = (const char*)(vN + (size_t)bh * HD * HW);

  __shared__ __align__(16) char smem[49152];
  char* pb = smem + 32768 + wid * 4096;

  int i0 = qt * 128 + wid * 32;

  // Q fragments, pre-scaled by (1/8)*log2(e) so softmax works in exp2 domain
  bf16x8 qf[2][2];
#pragma unroll
  for (int it = 0; it < 2; it++)
#pragma unroll
    for (int ks = 0; ks < 2; ks++) {
      int row = i0 + it * 16 + l15;
      bf16x8 qv = *(const bf16x8*)(qh + (size_t)row * HD + ks * 32 + lhi * 8);
#pragma unroll
      for (int e = 0; e < 8; e++) qv[e] = (__bf16)((float)qv[e] * 0.180336884f);
      qf[it][ks] = qv;
    }

  int sr = tid >> 3, sc = tid & 7;
  int sr2 = sr + 32;
  int swz1 = sr * 128 + ((sc ^ (sr & 7)) << 4);
  int swz2 = sr2 * 128 + ((sc ^ (sr2 & 7)) << 4);

  uint4 kr0, kr1, vr0, vr1;
  {
    kr0 = *(const uint4*)(kh + (size_t)sr * 128 + sc * 16);
    kr1 = *(const uint4*)(kh + (size_t)sr2 * 128 + sc * 16);
    vr0 = *(const uint4*)(vh + (size_t)sr * 2048 + sc * 16);
    vr1 = *(const uint4*)(vh + (size_t)sr2 * 2048 + sc * 16);
    *(uint4*)(smem + swz1) = kr0;
    *(uint4*)(smem + swz2) = kr1;
    *(uint4*)(smem + 8192 + swz1) = vr0;
    *(uint4*)(smem + 8192 + swz2) = vr1;
  }

  f32x4 accO[2][4] = {};
  f32x4 lacc[2] = {};
  float m[2][4];
#pragma unroll
  for (int it = 0; it < 2; it++)
#pragma unroll
    for (int r = 0; r < 4; r++) m[it][r] = -1e30f;

  bf16x8 ones;
#pragma unroll
  for (int e = 0; e < 8; e++) ones[e] = (__bf16)1.0f;

  for (int t = 0; t < 16; ++t) {
    if (t < 15) {
      int j0n = (t + 1) * 64;
      kr0 = *(const uint4*)(kh + (size_t)(j0n + sr) * 128 + sc * 16);
      kr1 = *(const uint4*)(kh + (size_t)(j0n + sr2) * 128 + sc * 16);
      vr0 = *(const uint4*)(vh + (size_t)sr * 2048 + j0n * 2 + sc * 16);
      vr1 = *(const uint4*)(vh + (size_t)sr2 * 2048 + j0n * 2 + sc * 16);
    }
    __syncthreads();
    const char* kt = smem + ((t & 1) << 14);
    const char* vt = kt + 8192;

    // ---- QK^T (scores already in log2 domain) ----
    f32x4 s_[2][4] = {};
#pragma unroll
    for (int ks = 0; ks < 2; ++ks)
#pragma unroll
      for (int jt = 0; jt < 4; ++jt) {
        int j = jt * 16 + l15;
        int c = ks * 4 + lhi;
        bf16x8 bk = *(const bf16x8*)(kt + j * 128 + ((c ^ (j & 7)) << 4));
        s_[0][jt] = __builtin_amdgcn_mfma_f32_16x16x32_bf16(qf[0][ks], bk, s_[0][jt], 0, 0, 0);
        s_[1][jt] = __builtin_amdgcn_mfma_f32_16x16x32_bf16(qf[1][ks], bk, s_[1][jt], 0, 0, 0);
      }

    // ---- defer-max online softmax (log2 domain) ----
    float lm[2][4];
    int ok = 1;
#pragma unroll
    for (int it = 0; it < 2; ++it)
#pragma unroll
      for (int r = 0; r < 4; r++) {
        lm[it][r] = fmaxf(fmaxf(s_[it][0][r], s_[it][1][r]),
                          fmaxf(s_[it][2][r], s_[it][3][r]));
        ok &= (lm[it][r] <= m[it][r] + 8.f);
      }
    if (!__all(ok)) {
#pragma unroll
      for (int it = 0; it < 2; ++it) {
        float pm[4];
#pragma unroll
        for (int r = 0; r < 4; r++) pm[r] = lm[it][r];
#pragma unroll
        for (int off = 1; off < 16; off <<= 1)
#pragma unroll
          for (int r = 0; r < 4; r++) pm[r] = fmaxf(pm[r], __shfl_xor(pm[r], off));
#pragma unroll
        for (int r = 0; r < 4; r++) {
          float nm = fmaxf(m[it][r], pm[r]);
          float corr = exp2f(m[it][r] - nm);
          m[it][r] = nm;
          lacc[it][r] *= corr;
#pragma unroll
          for (int dt = 0; dt < 4; ++dt) accO[it][dt][r] *= corr;
        }
      }
    }
    // P = 2^(s - m), store bf16 to per-wave LDS
#pragma unroll
    for (int it = 0; it < 2; ++it)
#pragma unroll
      for (int jt = 0; jt < 4; ++jt)
#pragma unroll
        for (int r = 0; r < 4; r++) {
          float p = exp2f(s_[it][jt][r] - m[it][r]);
          int row = it * 16 + lhi * 4 + r;
          int j = jt * 16 + l15;
          int off2 = row * 128 + (((j >> 3) ^ (row & 7)) << 4) + (j & 7) * 2;
          *(__bf16*)(pb + off2) = (__bf16)p;
        }

    // ---- PV + rowsum-by-MFMA ----
#pragma unroll
    for (int kj = 0; kj < 2; ++kj) {
      bf16x8 pa[2];
#pragma unroll
      for (int it = 0; it < 2; ++it) {
        int row = it * 16 + l15;
        int c = kj * 4 + lhi;
        pa[it] = *(const bf16x8*)(pb + row * 128 + ((c ^ (row & 7)) << 4));
      }
      lacc[0] = __builtin_amdgcn_mfma_f32_16x16x32_bf16(pa[0], ones, lacc[0], 0, 0, 0);
      lacc[1] = __builtin_amdgcn_mfma_f32_16x16x32_bf16(pa[1], ones, lacc[1], 0, 0, 0);
#pragma unroll
      for (int dt = 0; dt < 4; ++dt) {
        int d = dt * 16 + l15;
        int c = kj * 4 + lhi;
        bf16x8 bv = *(const bf16x8*)(vt + d * 128 + ((c ^ (d & 7)) << 4));
        accO[0][dt] = __builtin_amdgcn_mfma_f32_16x16x32_bf16(pa[0], bv, accO[0][dt], 0, 0, 0);
        accO[1][dt] = __builtin_amdgcn_mfma_f32_16x16x32_bf16(pa[1], bv, accO[1][dt], 0, 0, 0);
      }
    }

    if (t < 15) {
      char* ktn = smem + (((t + 1) & 1) << 14);
      *(uint4*)(ktn + swz1) = kr0;
      *(uint4*)(ktn + swz2) = kr1;
      *(uint4*)(ktn + 8192 + swz1) = vr0;
      *(uint4*)(ktn + 8192 + swz2) = vr1;
    }
  }

  // epilogue: per-wave LDS transpose -> aT[b][i][h*64+d] bf16 coalesced
  __syncthreads();
  __bf16* Lo = (__bf16*)(smem + wid * 4608);  // [32][72] bf16
#pragma unroll
  for (int it = 0; it < 2; ++it)
#pragma unroll
    for (int r = 0; r < 4; r++) {
      float inv = 1.f / lacc[it][r];
      int iloc = it * 16 + lhi * 4 + r;
#pragma unroll
      for (int dt = 0; dt < 4; ++dt)
        Lo[iloc * 72 + dt * 16 + l15] = (__bf16)(accO[it][dt][r] * inv);
    }
  __syncthreads();
  int b = bh >> 3, hh = bh & 7;
  int iloc = lane >> 1, dh = (lane & 1) * 32;
  __bf16* dst = aT + ((size_t)b * HW + i0 + iloc) * C + hh * 64 + dh;
  const __bf16* srcl = Lo + iloc * 72 + dh;
#pragma unroll
  for (int s2 = 0; s2 < 4; s2++)
    *(uint4*)(dst + s2 * 8) = *(const uint4*)(srcl + s2 * 8);
}

extern "C" void kernel_launch(void* const* d_in, const int* in_sizes, int n_in,
                              void* d_out, int out_size, void* d_ws, size_t ws_size,
                              hipStream_t stream) {
  const float* x = (const float*)d_in[0];
  const float* gamma = (const float*)d_in[1];
  const float* beta = (const float*)d_in[2];
  const float* w_qkv = (const float*)d_in[3];
  const float* b_qkv = (const float*)d_in[4];
  const float* w_out = (const float*)d_in[5];
  const float* b_out = (const float*)d_in[6];
  float* out = (float*)d_out;

  char* ws = (char*)d_ws;
  const size_t MB = 1024 * 1024;
  __bf16* xnT = (__bf16*)ws;                  // 8 MB [8][1024][512]
  __bf16* qT  = (__bf16*)(ws + 8 * MB);       // 8 MB [64][1024][64]
  __bf16* kT  = (__bf16*)(ws + 16 * MB);      // 8 MB
  __bf16* vN  = (__bf16*)(ws + 24 * MB);      // 8 MB [64][64][1024]
  __bf16* aT  = (__bf16*)(ws + 32 * MB);      // 8 MB [8][1024][512]
  __bf16* wbq = (__bf16*)(ws + 40 * MB);      // 1.5 MB [1536][512]
  __bf16* wbo = (__bf16*)(ws + 42 * MB);      // 0.5 MB [512][512]

  // 1. weights -> bf16
  wcvt_kernel<<<dim3(512), 256, 0, stream>>>(w_qkv, wbq, w_out, wbo);
  // 2. GroupNorm -> xnT bf16 [b][j][c]
  gn_kernel<<<dim3(256), 256, 0, stream>>>(x, gamma, beta, xnT);
  // 3. Q,K projection: D[j][o] = xnT @ Wqk^T
  gemm_rr<0><<<dim3(8, 8, 8), 256, 0, stream>>>(xnT, (size_t)HW * C, wbq, 0,
                                                b_qkv, qT, kT, nullptr, nullptr);
  // 4. V projection: D[d'][j] = Wv @ xnT^T
  gemm_rr<1><<<dim3(8, 4, 8), 256, 0, stream>>>(wbq + (size_t)1024 * 512, 0, xnT, (size_t)HW * C,
                                                b_qkv + 1024, vN, nullptr, nullptr, nullptr);
  // 5. MFMA flash attention -> aT bf16 [b][j][c] (XCD-local grid)
  attn_mfma_kernel<<<dim3(512), 256, 0, stream>>>(qT, kT, vN, aT);
  // 6. Output projection: D[o][j] = Wout @ aT^T + bias + residual
  gemm_rr<2><<<dim3(8, 4, 8), 256, 0, stream>>>(wbo, 0, aT, (size_t)HW * C,
                                                b_out, nullptr, nullptr, x, out);
}

// Round 12
// 176.587 us; speedup vs baseline: 1.6636x; 1.4629x over previous
//
#include <hip/hip_runtime.h>
#include <math.h>

#define NHEADS 8
#define C 512
#define HW 1024
#define HD 64

typedef __bf16 bf16x8 __attribute__((ext_vector_type(8)));
typedef __bf16 bf16x4 __attribute__((ext_vector_type(4)));
typedef float f32x4 __attribute__((ext_vector_type(4)));

// ---------------- weight fp32 -> bf16 convert (both W's in one launch) ------
__global__ __launch_bounds__(256) void wcvt_kernel(const float* __restrict__ w1,
                                                   __bf16* __restrict__ o1,
                                                   const float* __restrict__ w2,
                                                   __bf16* __restrict__ o2) {
  int id = blockIdx.x * 2048 + threadIdx.x * 8;
  const float* src;
  __bf16* dst;
  int off;
  if (id < 786432) { src = w1; dst = o1; off = id; }
  else { src = w2; dst = o2; off = id - 786432; }
  float4 a = *(const float4*)(src + off);
  float4 b = *(const float4*)(src + off + 4);
  bf16x8 o;
  o[0] = (__bf16)a.x; o[1] = (__bf16)a.y; o[2] = (__bf16)a.z; o[3] = (__bf16)a.w;
  o[4] = (__bf16)b.x; o[5] = (__bf16)b.y; o[6] = (__bf16)b.z; o[7] = (__bf16)b.w;
  *(bf16x8*)(dst + off) = o;
}

// ---------------- GroupNorm -> xnT [b][j=hw][c] bf16 ----------------
__global__ __launch_bounds__(256) void gn_kernel(const float* __restrict__ x,
                                                 const float* __restrict__ gamma,
                                                 const float* __restrict__ beta,
                                                 __bf16* __restrict__ xnT) {
  int b = blockIdx.x >> 5, g = blockIdx.x & 31;
  const size_t base = ((size_t)b * C + (size_t)g * 16) * HW;
  const float4* xp = (const float4*)(x + base);
  int tid = threadIdx.x;

  float s = 0.f, ss = 0.f;
  float4 v[16];
#pragma unroll
  for (int it = 0; it < 16; it++) {
    v[it] = xp[tid + it * 256];
    s += v[it].x + v[it].y + v[it].z + v[it].w;
    ss += v[it].x * v[it].x + v[it].y * v[it].y + v[it].z * v[it].z + v[it].w * v[it].w;
  }
#pragma unroll
  for (int off = 32; off > 0; off >>= 1) {
    s += __shfl_down(s, off);
    ss += __shfl_down(ss, off);
  }
  __shared__ float red[8];
  __shared__ float mi[2];
  int wid = tid >> 6;
  if ((tid & 63) == 0) { red[wid] = s; red[4 + wid] = ss; }
  __syncthreads();
  if (tid == 0) {
    float S = red[0] + red[1] + red[2] + red[3];
    float SS = red[4] + red[5] + red[6] + red[7];
    float mean = S * (1.f / 16384.f);
    float var = SS * (1.f / 16384.f) - mean * mean;
    mi[0] = mean;
    mi[1] = rsqrtf(var + 1e-5f);
  }
  __syncthreads();
  float mean = mi[0], inv = mi[1];
  float ga[16], be[16];
#pragma unroll
  for (int it = 0; it < 16; it++) {
    float g_ = gamma[g * 16 + it] * inv;
    ga[it] = g_;
    be[it] = beta[g * 16 + it] - mean * g_;
  }
  __bf16* dstb = xnT + ((size_t)b * HW + (size_t)tid * 4) * C + g * 16;
#pragma unroll
  for (int jj = 0; jj < 4; jj++) {
    bf16x8 w0, w1;
#pragma unroll
    for (int e = 0; e < 8; e++) {
      w0[e] = (__bf16)(((const float*)&v[e])[jj] * ga[e] + be[e]);
      w1[e] = (__bf16)(((const float*)&v[e + 8])[jj] * ga[e + 8] + be[e + 8]);
    }
    *(bf16x8*)(dstb + (size_t)jj * C) = w0;
    *(bf16x8*)(dstb + (size_t)jj * C + 8) = w1;
  }
}

// ---------------- MFMA GEMM: D = R @ C^T, both [rows][512] bf16 row-major ---
// Round-9 structure: 128x128 tile, BK=64, single-buffer, two barriers/iter.
// EPI 0: fused QKV epilogue — col<512 -> qT[i][d], col<1024 -> kT[i][d],
//        col>=1024 -> vN[d][i] (sec uniform per block since 512%128==0).
// EPI 2: D[o][j] -> Yout fp32 = D + bias + resid.
template <int EPI>
__global__ __launch_bounds__(256) void gemm_rr(const __bf16* __restrict__ Rp, size_t Rbs,
                                               const __bf16* __restrict__ Cp, size_t Cbs,
                                               const float* __restrict__ bias,
                                               __bf16* __restrict__ qT,
                                               __bf16* __restrict__ kT,
                                               __bf16* __restrict__ vN,
                                               const float* __restrict__ resid,
                                               float* __restrict__ Yout) {
  int bx = blockIdx.x, by = blockIdx.y, b = blockIdx.z;
  int tid = threadIdx.x, wid = tid >> 6, lane = tid & 63;
  int l15 = lane & 15, lhi = lane >> 4;
  int wr = wid >> 1, wc = wid & 1;

  const __bf16* Rb = Rp + (size_t)b * Rbs + (size_t)by * 128 * 512;
  const __bf16* Cb = Cp + (size_t)b * Cbs + (size_t)bx * 128 * 512;

  __shared__ __align__(16) char smem[32768];
  char* Rs = smem;
  char* Cs = smem + 16384;

  f32x4 acc[4][4] = {};
  int srow = tid >> 1, sc0 = (tid & 1) * 4;

  for (int kk = 0; kk < 512; kk += 64) {
    __syncthreads();
    const __bf16* rg = Rb + (size_t)srow * 512 + kk + sc0 * 8;
    const __bf16* cg = Cb + (size_t)srow * 512 + kk + sc0 * 8;
#pragma unroll
    for (int q = 0; q < 4; q++) {
      int c = sc0 + q;
      int o = srow * 128 + ((c ^ (srow & 7)) << 4);
      *(uint4*)(Rs + o) = *(const uint4*)(rg + q * 8);
      *(uint4*)(Cs + o) = *(const uint4*)(cg + q * 8);
    }
    __syncthreads();
#pragma unroll
    for (int ks = 0; ks < 2; ks++) {
      bf16x8 ar[4], br[4];
      int c = ks * 4 + lhi;
#pragma unroll
      for (int m = 0; m < 4; m++) {
        int row = wr * 64 + m * 16 + l15;
        ar[m] = *(const bf16x8*)(Rs + row * 128 + ((c ^ (row & 7)) << 4));
      }
#pragma unroll
      for (int n = 0; n < 4; n++) {
        int row = wc * 64 + n * 16 + l15;
        br[n] = *(const bf16x8*)(Cs + row * 128 + ((c ^ (row & 7)) << 4));
      }
#pragma unroll
      for (int m = 0; m < 4; m++)
#pragma unroll
        for (int n = 0; n < 4; n++)
          acc[m][n] = __builtin_amdgcn_mfma_f32_16x16x32_bf16(ar[m], br[n], acc[m][n], 0, 0, 0);
    }
  }

  int rbase = by * 128 + wr * 64;
  int cbase = bx * 128 + wc * 64;

  if (EPI == 0) {
#pragma unroll
    for (int n = 0; n < 4; n++) {
      int col = cbase + n * 16 + l15;  // 0..1535
      int sec = col >> 9;              // 0=Q, 1=K, 2=V (uniform per block)
      float bs = bias[col];
      if (sec < 2) {
        int h = (col >> 6) & 7;
        int d = col & 63;
        __bf16* dst0 = (sec ? kT : qT) + ((size_t)b * 8 + h) * (size_t)(HW * HD) + d;
#pragma unroll
        for (int m = 0; m < 4; m++)
#pragma unroll
          for (int r = 0; r < 4; r++) {
            int i = rbase + m * 16 + lhi * 4 + r;
            dst0[(size_t)i * HD] = (__bf16)(acc[m][n][r] + bs);
          }
      } else {
        int dp = col & 511;
        int h = dp >> 6, d = dp & 63;
        __bf16* dst = vN + (((size_t)b * 8 + h) * HD + d) * HW;
#pragma unroll
        for (int m = 0; m < 4; m++) {
          bf16x4 pk;
#pragma unroll
          for (int r = 0; r < 4; r++) pk[r] = (__bf16)(acc[m][n][r] + bs);
          *(bf16x4*)(dst + rbase + m * 16 + lhi * 4) = pk;
        }
      }
    }
  } else {
#pragma unroll
    for (int m = 0; m < 4; m++)
#pragma unroll
      for (int r = 0; r < 4; r++) {
        int o = rbase + m * 16 + lhi * 4 + r;
        float bs = bias[o];
        size_t base2 = ((size_t)b * C + o) * HW;
#pragma unroll
        for (int n = 0; n < 4; n++) {
          int j = cbase + n * 16 + l15;
          Yout[base2 + j] = acc[m][n][r] + bs + resid[base2 + j];
        }
      }
  }
}

// ---------------- MFMA flash attention (prefetch dbuf + defer-max + exp2) --
// qT,kT: [64 heads][1024][64] bf16 ; vN: [64 heads][64][1024] bf16
// Grid: flat 512; bh = id&63 so all 8 q-tiles of a head share one XCD's L2.
__global__ __launch_bounds__(256) void attn_mfma_kernel(const __bf16* __restrict__ qT,
                                                        const __bf16* __restrict__ kT,
                                                        const __bf16* __restrict__ vN,
                                                        __bf16* __restrict__ aT) {
  int bh = blockIdx.x & 63;
  int qt = blockIdx.x >> 6;
  int tid = threadIdx.x;
  int wid = tid >> 6;
  int lane = tid & 63;
  int l15 = lane & 15;
  int lhi = lane >> 4;

  const __bf16* qh = qT + (size_t)bh * HW * HD;
  const char* kh = (const char*)(kT + (size_t)bh * HW * HD);
  const char* vh = (const char*)(vN + (size_t)bh * HD * HW);

  __shared__ __align__(16) char smem[49152];
  char* pb = smem + 32768 + wid * 4096;

  int i0 = qt * 128 + wid * 32;

  // Q fragments, pre-scaled by (1/8)*log2(e) so softmax works in exp2 domain
  bf16x8 qf[2][2];
#pragma unroll
  for (int it = 0; it < 2; it++)
#pragma unroll
    for (int ks = 0; ks < 2; ks++) {
      int row = i0 + it * 16 + l15;
      bf16x8 qv = *(const bf16x8*)(qh + (size_t)row * HD + ks * 32 + lhi * 8);
#pragma unroll
      for (int e = 0; e < 8; e++) qv[e] = (__bf16)((float)qv[e] * 0.180336884f);
      qf[it][ks] = qv;
    }

  int sr = tid >> 3, sc = tid & 7;
  int sr2 = sr + 32;
  int swz1 = sr * 128 + ((sc ^ (sr & 7)) << 4);
  int swz2 = sr2 * 128 + ((sc ^ (sr2 & 7)) << 4);

  uint4 kr0, kr1, vr0, vr1;
  {
    kr0 = *(const uint4*)(kh + (size_t)sr * 128 + sc * 16);
    kr1 = *(const uint4*)(kh + (size_t)sr2 * 128 + sc * 16);
    vr0 = *(const uint4*)(vh + (size_t)sr * 2048 + sc * 16);
    vr1 = *(const uint4*)(vh + (size_t)sr2 * 2048 + sc * 16);
    *(uint4*)(smem + swz1) = kr0;
    *(uint4*)(smem + swz2) = kr1;
    *(uint4*)(smem + 8192 + swz1) = vr0;
    *(uint4*)(smem + 8192 + swz2) = vr1;
  }

  f32x4 accO[2][4] = {};
  f32x4 lacc[2] = {};
  float m[2][4];
#pragma unroll
  for (int it = 0; it < 2; it++)
#pragma unroll
    for (int r = 0; r < 4; r++) m[it][r] = -1e30f;

  bf16x8 ones;
#pragma unroll
  for (int e = 0; e < 8; e++) ones[e] = (__bf16)1.0f;

  for (int t = 0; t < 16; ++t) {
    if (t < 15) {
      int j0n = (t + 1) * 64;
      kr0 = *(const uint4*)(kh + (size_t)(j0n + sr) * 128 + sc * 16);
      kr1 = *(const uint4*)(kh + (size_t)(j0n + sr2) * 128 + sc * 16);
      vr0 = *(const uint4*)(vh + (size_t)sr * 2048 + j0n * 2 + sc * 16);
      vr1 = *(const uint4*)(vh + (size_t)sr2 * 2048 + j0n * 2 + sc * 16);
    }
    __syncthreads();
    const char* kt = smem + ((t & 1) << 14);
    const char* vt = kt + 8192;

    // ---- QK^T (scores already in log2 domain) ----
    f32x4 s_[2][4] = {};
#pragma unroll
    for (int ks = 0; ks < 2; ++ks)
#pragma unroll
      for (int jt = 0; jt < 4; ++jt) {
        int j = jt * 16 + l15;
        int c = ks * 4 + lhi;
        bf16x8 bk = *(const bf16x8*)(kt + j * 128 + ((c ^ (j & 7)) << 4));
        s_[0][jt] = __builtin_amdgcn_mfma_f32_16x16x32_bf16(qf[0][ks], bk, s_[0][jt], 0, 0, 0);
        s_[1][jt] = __builtin_amdgcn_mfma_f32_16x16x32_bf16(qf[1][ks], bk, s_[1][jt], 0, 0, 0);
      }

    // ---- defer-max online softmax (log2 domain) ----
    float lm[2][4];
    int ok = 1;
#pragma unroll
    for (int it = 0; it < 2; ++it)
#pragma unroll
      for (int r = 0; r < 4; r++) {
        lm[it][r] = fmaxf(fmaxf(s_[it][0][r], s_[it][1][r]),
                          fmaxf(s_[it][2][r], s_[it][3][r]));
        ok &= (lm[it][r] <= m[it][r] + 8.f);
      }
    if (!__all(ok)) {
#pragma unroll
      for (int it = 0; it < 2; ++it) {
        float pm[4];
#pragma unroll
        for (int r = 0; r < 4; r++) pm[r] = lm[it][r];
#pragma unroll
        for (int off = 1; off < 16; off <<= 1)
#pragma unroll
          for (int r = 0; r < 4; r++) pm[r] = fmaxf(pm[r], __shfl_xor(pm[r], off));
#pragma unroll
        for (int r = 0; r < 4; r++) {
          float nm = fmaxf(m[it][r], pm[r]);
          float corr = exp2f(m[it][r] - nm);
          m[it][r] = nm;
          lacc[it][r] *= corr;
#pragma unroll
          for (int dt = 0; dt < 4; ++dt) accO[it][dt][r] *= corr;
        }
      }
    }
    // P = 2^(s - m), store bf16 to per-wave LDS
#pragma unroll
    for (int it = 0; it < 2; ++it)
#pragma unroll
      for (int jt = 0; jt < 4; ++jt)
#pragma unroll
        for (int r = 0; r < 4; r++) {
          float p = exp2f(s_[it][jt][r] - m[it][r]);
          int row = it * 16 + lhi * 4 + r;
          int j = jt * 16 + l15;
          int off2 = row * 128 + (((j >> 3) ^ (row & 7)) << 4) + (j & 7) * 2;
          *(__bf16*)(pb + off2) = (__bf16)p;
        }

    // ---- PV + rowsum-by-MFMA ----
#pragma unroll
    for (int kj = 0; kj < 2; ++kj) {
      bf16x8 pa[2];
#pragma unroll
      for (int it = 0; it < 2; ++it) {
        int row = it * 16 + l15;
        int c = kj * 4 + lhi;
        pa[it] = *(const bf16x8*)(pb + row * 128 + ((c ^ (row & 7)) << 4));
      }
      lacc[0] = __builtin_amdgcn_mfma_f32_16x16x32_bf16(pa[0], ones, lacc[0], 0, 0, 0);
      lacc[1] = __builtin_amdgcn_mfma_f32_16x16x32_bf16(pa[1], ones, lacc[1], 0, 0, 0);
#pragma unroll
      for (int dt = 0; dt < 4; ++dt) {
        int d = dt * 16 + l15;
        int c = kj * 4 + lhi;
        bf16x8 bv = *(const bf16x8*)(vt + d * 128 + ((c ^ (d & 7)) << 4));
        accO[0][dt] = __builtin_amdgcn_mfma_f32_16x16x32_bf16(pa[0], bv, accO[0][dt], 0, 0, 0);
        accO[1][dt] = __builtin_amdgcn_mfma_f32_16x16x32_bf16(pa[1], bv, accO[1][dt], 0, 0, 0);
      }
    }

    if (t < 15) {
      char* ktn = smem + (((t + 1) & 1) << 14);
      *(uint4*)(ktn + swz1) = kr0;
      *(uint4*)(ktn + swz2) = kr1;
      *(uint4*)(ktn + 8192 + swz1) = vr0;
      *(uint4*)(ktn + 8192 + swz2) = vr1;
    }
  }

  // epilogue: per-wave LDS transpose -> aT[b][i][h*64+d] bf16 coalesced
  __syncthreads();
  __bf16* Lo = (__bf16*)(smem + wid * 4608);  // [32][72] bf16
#pragma unroll
  for (int it = 0; it < 2; ++it)
#pragma unroll
    for (int r = 0; r < 4; r++) {
      float inv = 1.f / lacc[it][r];
      int iloc = it * 16 + lhi * 4 + r;
#pragma unroll
      for (int dt = 0; dt < 4; ++dt)
        Lo[iloc * 72 + dt * 16 + l15] = (__bf16)(accO[it][dt][r] * inv);
    }
  __syncthreads();
  int b = bh >> 3, hh = bh & 7;
  int iloc = lane >> 1, dh = (lane & 1) * 32;
  __bf16* dst = aT + ((size_t)b * HW + i0 + iloc) * C + hh * 64 + dh;
  const __bf16* srcl = Lo + iloc * 72 + dh;
#pragma unroll
  for (int s2 = 0; s2 < 4; s2++)
    *(uint4*)(dst + s2 * 8) = *(const uint4*)(srcl + s2 * 8);
}

extern "C" void kernel_launch(void* const* d_in, const int* in_sizes, int n_in,
                              void* d_out, int out_size, void* d_ws, size_t ws_size,
                              hipStream_t stream) {
  const float* x = (const float*)d_in[0];
  const float* gamma = (const float*)d_in[1];
  const float* beta = (const float*)d_in[2];
  const float* w_qkv = (const float*)d_in[3];
  const float* b_qkv = (const float*)d_in[4];
  const float* w_out = (const float*)d_in[5];
  const float* b_out = (const float*)d_in[6];
  float* out = (float*)d_out;

  char* ws = (char*)d_ws;
  const size_t MB = 1024 * 1024;
  __bf16* xnT = (__bf16*)ws;                  // 8 MB [8][1024][512]
  __bf16* qT  = (__bf16*)(ws + 8 * MB);       // 8 MB [64][1024][64]
  __bf16* kT  = (__bf16*)(ws + 16 * MB);      // 8 MB
  __bf16* vN  = (__bf16*)(ws + 24 * MB);      // 8 MB [64][64][1024]
  __bf16* aT  = (__bf16*)(ws + 32 * MB);      // 8 MB [8][1024][512]
  __bf16* wbq = (__bf16*)(ws + 40 * MB);      // 1.5 MB [1536][512]
  __bf16* wbo = (__bf16*)(ws + 42 * MB);      // 0.5 MB [512][512]

  // 1. weights -> bf16
  wcvt_kernel<<<dim3(512), 256, 0, stream>>>(w_qkv, wbq, w_out, wbo);
  // 2. GroupNorm -> xnT bf16 [b][j][c]
  gn_kernel<<<dim3(256), 256, 0, stream>>>(x, gamma, beta, xnT);
  // 3. Fused QKV projection: D[j][col] = xnT @ Wqkv^T, col 0..1535
  gemm_rr<0><<<dim3(12, 8, 8), 256, 0, stream>>>(xnT, (size_t)HW * C, wbq, 0,
                                                 b_qkv, qT, kT, vN, nullptr, nullptr);
  // 4. MFMA flash attention -> aT bf16 [b][j][c] (XCD-local grid)
  attn_mfma_kernel<<<dim3(512), 256, 0, stream>>>(qT, kT, vN, aT);
  // 5. Output projection: D[o][j] = Wout @ aT^T + bias + residual
  gemm_rr<2><<<dim3(8, 4, 8), 256, 0, stream>>>(wbo, 0, aT, (size_t)HW * C,
                                                b_out, nullptr, nullptr, nullptr, x, out);
}

// Round 13
// 167.150 us; speedup vs baseline: 1.7575x; 1.0565x over previous
//
#include <hip/hip_runtime.h>
#include <math.h>

#define NHEADS 8
#define C 512
#define HW 1024
#define HD 64

typedef __bf16 bf16x8 __attribute__((ext_vector_type(8)));
typedef __bf16 bf16x4 __attribute__((ext_vector_type(4)));
typedef float f32x4 __attribute__((ext_vector_type(4)));

#if __has_builtin(__builtin_amdgcn_exp2f)
#define EXP2(x) __builtin_amdgcn_exp2f(x)
#else
#define EXP2(x) __expf((x) * 0.6931471805599453f)
#endif

#define GAS(p) ((const __attribute__((address_space(1))) uint32_t*)(p))
#define LAS(p) ((__attribute__((address_space(3))) uint32_t*)(p))

// ---------------- weight fp32 -> bf16 convert (both W's in one launch) ------
__global__ __launch_bounds__(256) void wcvt_kernel(const float* __restrict__ w1,
                                                   __bf16* __restrict__ o1,
                                                   const float* __restrict__ w2,
                                                   __bf16* __restrict__ o2) {
  int id = blockIdx.x * 2048 + threadIdx.x * 8;
  const float* src;
  __bf16* dst;
  int off;
  if (id < 786432) { src = w1; dst = o1; off = id; }
  else { src = w2; dst = o2; off = id - 786432; }
  float4 a = *(const float4*)(src + off);
  float4 b = *(const float4*)(src + off + 4);
  bf16x8 o;
  o[0] = (__bf16)a.x; o[1] = (__bf16)a.y; o[2] = (__bf16)a.z; o[3] = (__bf16)a.w;
  o[4] = (__bf16)b.x; o[5] = (__bf16)b.y; o[6] = (__bf16)b.z; o[7] = (__bf16)b.w;
  *(bf16x8*)(dst + off) = o;
}

// ---------------- GroupNorm -> xnT [b][j=hw][c] bf16 ----------------
__global__ __launch_bounds__(256) void gn_kernel(const float* __restrict__ x,
                                                 const float* __restrict__ gamma,
                                                 const float* __restrict__ beta,
                                                 __bf16* __restrict__ xnT) {
  int b = blockIdx.x >> 5, g = blockIdx.x & 31;
  const size_t base = ((size_t)b * C + (size_t)g * 16) * HW;
  const float4* xp = (const float4*)(x + base);
  int tid = threadIdx.x;

  float s = 0.f, ss = 0.f;
  float4 v[16];
#pragma unroll
  for (int it = 0; it < 16; it++) {
    v[it] = xp[tid + it * 256];
    s += v[it].x + v[it].y + v[it].z + v[it].w;
    ss += v[it].x * v[it].x + v[it].y * v[it].y + v[it].z * v[it].z + v[it].w * v[it].w;
  }
#pragma unroll
  for (int off = 32; off > 0; off >>= 1) {
    s += __shfl_down(s, off);
    ss += __shfl_down(ss, off);
  }
  __shared__ float red[8];
  __shared__ float mi[2];
  int wid = tid >> 6;
  if ((tid & 63) == 0) { red[wid] = s; red[4 + wid] = ss; }
  __syncthreads();
  if (tid == 0) {
    float S = red[0] + red[1] + red[2] + red[3];
    float SS = red[4] + red[5] + red[6] + red[7];
    float mean = S * (1.f / 16384.f);
    float var = SS * (1.f / 16384.f) - mean * mean;
    mi[0] = mean;
    mi[1] = rsqrtf(var + 1e-5f);
  }
  __syncthreads();
  float mean = mi[0], inv = mi[1];
  float ga[16], be[16];
#pragma unroll
  for (int it = 0; it < 16; it++) {
    float g_ = gamma[g * 16 + it] * inv;
    ga[it] = g_;
    be[it] = beta[g * 16 + it] - mean * g_;
  }
  __bf16* dstb = xnT + ((size_t)b * HW + (size_t)tid * 4) * C + g * 16;
#pragma unroll
  for (int jj = 0; jj < 4; jj++) {
    bf16x8 w0, w1;
#pragma unroll
    for (int e = 0; e < 8; e++) {
      w0[e] = (__bf16)(((const float*)&v[e])[jj] * ga[e] + be[e]);
      w1[e] = (__bf16)(((const float*)&v[e + 8])[jj] * ga[e + 8] + be[e + 8]);
    }
    *(bf16x8*)(dstb + (size_t)jj * C) = w0;
    *(bf16x8*)(dstb + (size_t)jj * C + 8) = w1;
  }
}

// ---------------- MFMA GEMM: D = R @ C^T, both [rows][512] bf16 row-major ---
// 128x128 tile, BK=64, global_load_lds(16B) staging with pre-swizzled global
// source + linear-in-lane LDS dest (slot (r,cc) holds source chunk (r,cc^(r&7))
// so the swizzled read finds chunk (r,c) at cc=c^(r&7)).
// EPI 0: fused QKV epilogue; EPI 2: out fp32 + bias + resid.
template <int EPI>
__global__ __launch_bounds__(256) void gemm_rr(const __bf16* __restrict__ Rp, size_t Rbs,
                                               const __bf16* __restrict__ Cp, size_t Cbs,
                                               const float* __restrict__ bias,
                                               __bf16* __restrict__ qT,
                                               __bf16* __restrict__ kT,
                                               __bf16* __restrict__ vN,
                                               const float* __restrict__ resid,
                                               float* __restrict__ Yout) {
  int bx = blockIdx.x, by = blockIdx.y, b = blockIdx.z;
  int tid = threadIdx.x, wid = tid >> 6, lane = tid & 63;
  int l15 = lane & 15, lhi = lane >> 4;
  int wr = wid >> 1, wc = wid & 1;

  const __bf16* Rb = Rp + (size_t)b * Rbs + (size_t)by * 128 * 512;
  const __bf16* Cb = Cp + (size_t)b * Cbs + (size_t)bx * 128 * 512;

  __shared__ __align__(16) char smem[32768];  // Rs 16K, Cs 16K

  f32x4 acc[4][4] = {};

  // staging geometry: wave w, call q, lane L -> LDS slot w*4096+q*1024+L*16
  // = row r = w*32+q*8+(L>>3), chunk cc = L&7; source chunk = (r, cc^(r&7)).
  int rA = wid * 32 + (lane >> 3);
  int ccx = lane & 7;

  for (int kk = 0; kk < 512; kk += 64) {
    __syncthreads();
#pragma unroll
    for (int q = 0; q < 4; q++) {
      int r = rA + q * 8;
      int cs = ((ccx ^ (r & 7)) << 3);  // source element offset within K-slice
      const __bf16* rsrc = Rb + (size_t)r * 512 + kk + cs;
      const __bf16* csrc = Cb + (size_t)r * 512 + kk + cs;
      char* ldst = smem + wid * 4096 + q * 1024;  // wave-uniform; lane adds L*16
      __builtin_amdgcn_global_load_lds(GAS(rsrc), LAS(ldst), 16, 0, 0);
      __builtin_amdgcn_global_load_lds(GAS(csrc), LAS(ldst + 16384), 16, 0, 0);
    }
    __syncthreads();
#pragma unroll
    for (int ks = 0; ks < 2; ks++) {
      bf16x8 ar[4], br[4];
      int c = ks * 4 + lhi;
#pragma unroll
      for (int m = 0; m < 4; m++) {
        int row = wr * 64 + m * 16 + l15;
        ar[m] = *(const bf16x8*)(smem + row * 128 + ((c ^ (row & 7)) << 4));
      }
#pragma unroll
      for (int n = 0; n < 4; n++) {
        int row = wc * 64 + n * 16 + l15;
        br[n] = *(const bf16x8*)(smem + 16384 + row * 128 + ((c ^ (row & 7)) << 4));
      }
#pragma unroll
      for (int m = 0; m < 4; m++)
#pragma unroll
        for (int n = 0; n < 4; n++)
          acc[m][n] = __builtin_amdgcn_mfma_f32_16x16x32_bf16(ar[m], br[n], acc[m][n], 0, 0, 0);
    }
  }

  int rbase = by * 128 + wr * 64;
  int cbase = bx * 128 + wc * 64;

  if (EPI == 0) {
#pragma unroll
    for (int n = 0; n < 4; n++) {
      int col = cbase + n * 16 + l15;  // 0..1535
      int sec = col >> 9;              // 0=Q, 1=K, 2=V (uniform per block)
      float bs = bias[col];
      if (sec < 2) {
        int h = (col >> 6) & 7;
        int d = col & 63;
        __bf16* dst0 = (sec ? kT : qT) + ((size_t)b * 8 + h) * (size_t)(HW * HD) + d;
#pragma unroll
        for (int m = 0; m < 4; m++)
#pragma unroll
          for (int r = 0; r < 4; r++) {
            int i = rbase + m * 16 + lhi * 4 + r;
            dst0[(size_t)i * HD] = (__bf16)(acc[m][n][r] + bs);
          }
      } else {
        int dp = col & 511;
        int h = dp >> 6, d = dp & 63;
        __bf16* dst = vN + (((size_t)b * 8 + h) * HD + d) * HW;
#pragma unroll
        for (int m = 0; m < 4; m++) {
          bf16x4 pk;
#pragma unroll
          for (int r = 0; r < 4; r++) pk[r] = (__bf16)(acc[m][n][r] + bs);
          *(bf16x4*)(dst + rbase + m * 16 + lhi * 4) = pk;
        }
      }
    }
  } else {
#pragma unroll
    for (int m = 0; m < 4; m++)
#pragma unroll
      for (int r = 0; r < 4; r++) {
        int o = rbase + m * 16 + lhi * 4 + r;
        float bs = bias[o];
        size_t base2 = ((size_t)b * C + o) * HW;
#pragma unroll
        for (int n = 0; n < 4; n++) {
          int j = cbase + n * 16 + l15;
          Yout[base2 + j] = acc[m][n][r] + bs + resid[base2 + j];
        }
      }
  }
}

// ---------------- MFMA flash attention (prefetch dbuf + defer-max + exp2) --
// qT,kT: [64 heads][1024][64] bf16 ; vN: [64 heads][64][1024] bf16
// Grid: flat 512; bh = id&63 so all 8 q-tiles of a head share one XCD's L2.
__global__ __launch_bounds__(256) void attn_mfma_kernel(const __bf16* __restrict__ qT,
                                                        const __bf16* __restrict__ kT,
                                                        const __bf16* __restrict__ vN,
                                                        __bf16* __restrict__ aT) {
  int bh = blockIdx.x & 63;
  int qt = blockIdx.x >> 6;
  int tid = threadIdx.x;
  int wid = tid >> 6;
  int lane = tid & 63;
  int l15 = lane & 15;
  int lhi = lane >> 4;

  const __bf16* qh = qT + (size_t)bh * HW * HD;
  const char* kh = (const char*)(kT + (size_t)bh * HW * HD);
  const char* vh = (const char*)(vN + (size_t)bh * HD * HW);

  __shared__ __align__(16) char smem[49152];
  char* pb = smem + 32768 + wid * 4096;

  int i0 = qt * 128 + wid * 32;

  // Q fragments, pre-scaled by (1/8)*log2(e) so softmax works in exp2 domain
  bf16x8 qf[2][2];
#pragma unroll
  for (int it = 0; it < 2; it++)
#pragma unroll
    for (int ks = 0; ks < 2; ks++) {
      int row = i0 + it * 16 + l15;
      bf16x8 qv = *(const bf16x8*)(qh + (size_t)row * HD + ks * 32 + lhi * 8);
#pragma unroll
      for (int e = 0; e < 8; e++) qv[e] = (__bf16)((float)qv[e] * 0.180336884f);
      qf[it][ks] = qv;
    }

  int sr = tid >> 3, sc = tid & 7;
  int sr2 = sr + 32;
  int swz1 = sr * 128 + ((sc ^ (sr & 7)) << 4);
  int swz2 = sr2 * 128 + ((sc ^ (sr2 & 7)) << 4);

  uint4 kr0, kr1, vr0, vr1;
  {
    kr0 = *(const uint4*)(kh + (size_t)sr * 128 + sc * 16);
    kr1 = *(const uint4*)(kh + (size_t)sr2 * 128 + sc * 16);
    vr0 = *(const uint4*)(vh + (size_t)sr * 2048 + sc * 16);
    vr1 = *(const uint4*)(vh + (size_t)sr2 * 2048 + sc * 16);
    *(uint4*)(smem + swz1) = kr0;
    *(uint4*)(smem + swz2) = kr1;
    *(uint4*)(smem + 8192 + swz1) = vr0;
    *(uint4*)(smem + 8192 + swz2) = vr1;
  }

  f32x4 accO[2][4] = {};
  f32x4 lacc[2] = {};
  float m[2][4];
#pragma unroll
  for (int it = 0; it < 2; it++)
#pragma unroll
    for (int r = 0; r < 4; r++) m[it][r] = -1e30f;

  bf16x8 ones;
#pragma unroll
  for (int e = 0; e < 8; e++) ones[e] = (__bf16)1.0f;

  for (int t = 0; t < 16; ++t) {
    if (t < 15) {
      int j0n = (t + 1) * 64;
      kr0 = *(const uint4*)(kh + (size_t)(j0n + sr) * 128 + sc * 16);
      kr1 = *(const uint4*)(kh + (size_t)(j0n + sr2) * 128 + sc * 16);
      vr0 = *(const uint4*)(vh + (size_t)sr * 2048 + j0n * 2 + sc * 16);
      vr1 = *(const uint4*)(vh + (size_t)sr2 * 2048 + j0n * 2 + sc * 16);
    }
    __syncthreads();
    const char* kt = smem + ((t & 1) << 14);
    const char* vt = kt + 8192;

    // ---- QK^T (scores already in log2 domain) ----
    f32x4 s_[2][4] = {};
#pragma unroll
    for (int ks = 0; ks < 2; ++ks)
#pragma unroll
      for (int jt = 0; jt < 4; ++jt) {
        int j = jt * 16 + l15;
        int c = ks * 4 + lhi;
        bf16x8 bk = *(const bf16x8*)(kt + j * 128 + ((c ^ (j & 7)) << 4));
        s_[0][jt] = __builtin_amdgcn_mfma_f32_16x16x32_bf16(qf[0][ks], bk, s_[0][jt], 0, 0, 0);
        s_[1][jt] = __builtin_amdgcn_mfma_f32_16x16x32_bf16(qf[1][ks], bk, s_[1][jt], 0, 0, 0);
      }

    // ---- defer-max online softmax (log2 domain) ----
    float lm[2][4];
    int ok = 1;
#pragma unroll
    for (int it = 0; it < 2; ++it)
#pragma unroll
      for (int r = 0; r < 4; r++) {
        lm[it][r] = fmaxf(fmaxf(s_[it][0][r], s_[it][1][r]),
                          fmaxf(s_[it][2][r], s_[it][3][r]));
        ok &= (lm[it][r] <= m[it][r] + 8.f);
      }
    if (!__all(ok)) {
#pragma unroll
      for (int it = 0; it < 2; ++it) {
        float pm[4];
#pragma unroll
        for (int r = 0; r < 4; r++) pm[r] = lm[it][r];
#pragma unroll
        for (int off = 1; off < 16; off <<= 1)
#pragma unroll
          for (int r = 0; r < 4; r++) pm[r] = fmaxf(pm[r], __shfl_xor(pm[r], off));
#pragma unroll
        for (int r = 0; r < 4; r++) {
          float nm = fmaxf(m[it][r], pm[r]);
          float corr = EXP2(m[it][r] - nm);
          m[it][r] = nm;
          lacc[it][r] *= corr;
#pragma unroll
          for (int dt = 0; dt < 4; ++dt) accO[it][dt][r] *= corr;
        }
      }
    }
    // P = 2^(s - m), store bf16 to per-wave LDS
#pragma unroll
    for (int it = 0; it < 2; ++it)
#pragma unroll
      for (int jt = 0; jt < 4; ++jt)
#pragma unroll
        for (int r = 0; r < 4; r++) {
          float p = EXP2(s_[it][jt][r] - m[it][r]);
          int row = it * 16 + lhi * 4 + r;
          int j = jt * 16 + l15;
          int off2 = row * 128 + (((j >> 3) ^ (row & 7)) << 4) + (j & 7) * 2;
          *(__bf16*)(pb + off2) = (__bf16)p;
        }

    // ---- PV + rowsum-by-MFMA ----
#pragma unroll
    for (int kj = 0; kj < 2; ++kj) {
      bf16x8 pa[2];
#pragma unroll
      for (int it = 0; it < 2; ++it) {
        int row = it * 16 + l15;
        int c = kj * 4 + lhi;
        pa[it] = *(const bf16x8*)(pb + row * 128 + ((c ^ (row & 7)) << 4));
      }
      lacc[0] = __builtin_amdgcn_mfma_f32_16x16x32_bf16(pa[0], ones, lacc[0], 0, 0, 0);
      lacc[1] = __builtin_amdgcn_mfma_f32_16x16x32_bf16(pa[1], ones, lacc[1], 0, 0, 0);
#pragma unroll
      for (int dt = 0; dt < 4; ++dt) {
        int d = dt * 16 + l15;
        int c = kj * 4 + lhi;
        bf16x8 bv = *(const bf16x8*)(vt + d * 128 + ((c ^ (d & 7)) << 4));
        accO[0][dt] = __builtin_amdgcn_mfma_f32_16x16x32_bf16(pa[0], bv, accO[0][dt], 0, 0, 0);
        accO[1][dt] = __builtin_amdgcn_mfma_f32_16x16x32_bf16(pa[1], bv, accO[1][dt], 0, 0, 0);
      }
    }

    if (t < 15) {
      char* ktn = smem + (((t + 1) & 1) << 14);
      *(uint4*)(ktn + swz1) = kr0;
      *(uint4*)(ktn + swz2) = kr1;
      *(uint4*)(ktn + 8192 + swz1) = vr0;
      *(uint4*)(ktn + 8192 + swz2) = vr1;
    }
  }

  // epilogue: per-wave LDS transpose -> aT[b][i][h*64+d] bf16 coalesced
  __syncthreads();
  __bf16* Lo = (__bf16*)(smem + wid * 4608);  // [32][72] bf16
#pragma unroll
  for (int it = 0; it < 2; ++it)
#pragma unroll
    for (int r = 0; r < 4; r++) {
      float inv = 1.f / lacc[it][r];
      int iloc = it * 16 + lhi * 4 + r;
#pragma unroll
      for (int dt = 0; dt < 4; ++dt)
        Lo[iloc * 72 + dt * 16 + l15] = (__bf16)(accO[it][dt][r] * inv);
    }
  __syncthreads();
  int b = bh >> 3, hh = bh & 7;
  int iloc = lane >> 1, dh = (lane & 1) * 32;
  __bf16* dst = aT + ((size_t)b * HW + i0 + iloc) * C + hh * 64 + dh;
  const __bf16* srcl = Lo + iloc * 72 + dh;
#pragma unroll
  for (int s2 = 0; s2 < 4; s2++)
    *(uint4*)(dst + s2 * 8) = *(const uint4*)(srcl + s2 * 8);
}

extern "C" void kernel_launch(void* const* d_in, const int* in_sizes, int n_in,
                              void* d_out, int out_size, void* d_ws, size_t ws_size,
                              hipStream_t stream) {
  const float* x = (const float*)d_in[0];
  const float* gamma = (const float*)d_in[1];
  const float* beta = (const float*)d_in[2];
  const float* w_qkv = (const float*)d_in[3];
  const float* b_qkv = (const float*)d_in[4];
  const float* w_out = (const float*)d_in[5];
  const float* b_out = (const float*)d_in[6];
  float* out = (float*)d_out;

  char* ws = (char*)d_ws;
  const size_t MB = 1024 * 1024;
  __bf16* xnT = (__bf16*)ws;                  // 8 MB [8][1024][512]
  __bf16* qT  = (__bf16*)(ws + 8 * MB);       // 8 MB [64][1024][64]
  __bf16* kT  = (__bf16*)(ws + 16 * MB);      // 8 MB
  __bf16* vN  = (__bf16*)(ws + 24 * MB);      // 8 MB [64][64][1024]
  __bf16* aT  = (__bf16*)(ws + 32 * MB);      // 8 MB [8][1024][512]
  __bf16* wbq = (__bf16*)(ws + 40 * MB);      // 1.5 MB [1536][512]
  __bf16* wbo = (__bf16*)(ws + 42 * MB);      // 0.5 MB [512][512]

  // 1. weights -> bf16
  wcvt_kernel<<<dim3(512), 256, 0, stream>>>(w_qkv, wbq, w_out, wbo);
  // 2. GroupNorm -> xnT bf16 [b][j][c]
  gn_kernel<<<dim3(256), 256, 0, stream>>>(x, gamma, beta, xnT);
  // 3. Fused QKV projection: D[j][col] = xnT @ Wqkv^T, col 0..1535
  gemm_rr<0><<<dim3(12, 8, 8), 256, 0, stream>>>(xnT, (size_t)HW * C, wbq, 0,
                                                 b_qkv, qT, kT, vN, nullptr, nullptr);
  // 4. MFMA flash attention -> aT bf16 [b][j][c] (XCD-local grid)
  attn_mfma_kernel<<<dim3(512), 256, 0, stream>>>(qT, kT, vN, aT);
  // 5. Output projection: D[o][j] = Wout @ aT^T + bias + residual
  gemm_rr<2><<<dim3(8, 4, 8), 256, 0, stream>>>(wbo, 0, aT, (size_t)HW * C,
                                                b_out, nullptr, nullptr, nullptr, x, out);
}